// Round 3
// baseline (428.286 us; speedup 1.0000x reference)
//
#include <hip/hip_runtime.h>

#define T_TERMS 768
#define NV 6
#define D1 5
#define D2 9
#define T2 (T_TERMS * T_TERMS)            // 589824
#define PTOT (T2 + T_TERMS + 1)           // 590593
#define NOUT ((unsigned int)PTOT * NV * D2) // 31,892,022 per tensor

// Bernstein product weights W[i][j] = C(4,i)*C(4,j)/C(8,i+j)
__device__ __constant__ float Wc[5][5] = {
    {1.0f,        4.0f/8.0f,   6.0f/28.0f,  4.0f/56.0f,  1.0f/70.0f},
    {4.0f/8.0f,   16.0f/28.0f, 24.0f/56.0f, 16.0f/70.0f, 4.0f/56.0f},
    {6.0f/28.0f,  24.0f/56.0f, 36.0f/70.0f, 24.0f/56.0f, 6.0f/28.0f},
    {4.0f/56.0f,  16.0f/70.0f, 24.0f/56.0f, 16.0f/28.0f, 4.0f/8.0f},
    {1.0f/70.0f,  4.0f/56.0f,  6.0f/28.0f,  4.0f/8.0f,   1.0f}
};

// Kernel 1: interval bounds l (under) and u (over) + relu relaxation coeffs.
// One block, 768 threads (one per term).
__global__ void bounds_kernel(const float* __restrict__ Pu,
                              const float* __restrict__ Po,
                              float* __restrict__ coef) {
    int t = threadIdx.x;
    float tlo = 0.f, thi = 0.f;
    if (t < T_TERMS) {
        float clo_u = 1.f, chi_u = 1.f;
        float clo_o = 1.f, chi_o = 1.f;
        const float* pu = Pu + t * NV * D1;
        const float* po = Po + t * NV * D1;
        #pragma unroll
        for (int v = 0; v < NV; ++v) {
            // under
            float lo = pu[v * 5 + 0], hi = lo;
            #pragma unroll
            for (int i = 1; i < 5; ++i) {
                float x = pu[v * 5 + i];
                lo = fminf(lo, x); hi = fmaxf(hi, x);
            }
            float a = clo_u * lo, b = clo_u * hi, c = chi_u * lo, d = chi_u * hi;
            clo_u = fminf(fminf(a, b), fminf(c, d));
            chi_u = fmaxf(fmaxf(a, b), fmaxf(c, d));
            // over
            lo = po[v * 5 + 0]; hi = lo;
            #pragma unroll
            for (int i = 1; i < 5; ++i) {
                float x = po[v * 5 + i];
                lo = fminf(lo, x); hi = fmaxf(hi, x);
            }
            a = clo_o * lo; b = clo_o * hi; c = chi_o * lo; d = chi_o * hi;
            clo_o = fminf(fminf(a, b), fminf(c, d));
            chi_o = fmaxf(fmaxf(a, b), fmaxf(c, d));
        }
        tlo = clo_u;   // lower bound contribution (under)
        thi = chi_o;   // upper bound contribution (over)
    }
    // reduce across 12 waves (wave64 butterfly via shfl_down from 32)
    __shared__ float slo[12], shi[12];
    for (int off = 32; off; off >>= 1) {
        tlo += __shfl_down(tlo, off);
        thi += __shfl_down(thi, off);
    }
    int wave = threadIdx.x >> 6;
    if ((threadIdx.x & 63) == 0) { slo[wave] = tlo; shi[wave] = thi; }
    __syncthreads();
    if (threadIdx.x == 0) {
        float l = 0.f, u = 0.f;
        #pragma unroll
        for (int w = 0; w < 12; ++w) { l += slo[w]; u += shi[w]; }
        float den = (u - l > 0.f) ? (u - l) : 1.f;
        float au, bu, cu, ao, bo, co;
        if (l >= 0.f) {
            au = 0.f; bu = 1.f; cu = 0.f;
            ao = 0.f; bo = 1.f; co = 0.f;
        } else if (u <= 0.f) {
            au = bu = cu = 0.f;
            ao = bo = co = 0.f;
        } else {
            au = 1.f / den; bu = -l / den; cu = 0.f;
            float d2 = den * den;
            ao = u / d2; bo = -2.f * u * l / d2; co = u * l * l / d2;
        }
        coef[0] = au; coef[1] = bu; coef[2] = cu;
        coef[3] = ao; coef[4] = bo; coef[5] = co;
    }
}

// Kernel 2: expand to ((T^2+T+1)*V, D2) per tensor; one thread per output f32.
// blockIdx.y selects tensor (0 = under, 1 = over).
__global__ void expand_kernel(const float* __restrict__ Pu,
                              const float* __restrict__ Po,
                              const float* __restrict__ coef,
                              float* __restrict__ out) {
    unsigned int idx = blockIdx.x * blockDim.x + threadIdx.x;
    if (idx >= NOUT) return;
    const float* P = blockIdx.y ? Po : Pu;
    const float* c3 = coef + (blockIdx.y ? 3 : 0);
    float* o = out + (size_t)blockIdx.y * NOUT;

    unsigned int k = idx % 9u;
    unsigned int r = idx / 9u;
    unsigned int v = r % 6u;
    unsigned int p = r / 6u;

    float val;
    if (p < (unsigned int)T2) {
        unsigned int t = p / (unsigned int)T_TERMS;
        unsigned int s = p % (unsigned int)T_TERMS;
        const float* A = P + (t * NV + v) * D1;
        const float* B = P + (s * NV + v) * D1;
        int ilo = (int)k - 4 > 0 ? (int)k - 4 : 0;
        int ihi = (int)k < 4 ? (int)k : 4;
        float acc = 0.f;
        #pragma unroll 5
        for (int i = ilo; i <= ihi; ++i)
            acc = fmaf(Wc[i][k - i] * A[i], B[k - i], acc);
        val = acc;
        if (v == 0u) val *= c3[0];
    } else if (p < (unsigned int)(T2 + T_TERMS)) {
        unsigned int t = p - (unsigned int)T2;
        const float* A = P + (t * NV + v) * D1;
        int ilo = (int)k - 4 > 0 ? (int)k - 4 : 0;
        int ihi = (int)k < 4 ? (int)k : 4;
        float acc = 0.f;
        #pragma unroll 5
        for (int i = ilo; i <= ihi; ++i)
            acc = fmaf(Wc[i][k - i], A[i], acc);
        val = acc;
        if (v == 0u) val *= c3[1];
    } else {
        val = (v == 0u) ? c3[2] : 1.f;
    }
    // write-once 255 MB stream: bypass L2 write-allocate
    __builtin_nontemporal_store(val, o + idx);
}

extern "C" void kernel_launch(void* const* d_in, const int* in_sizes, int n_in,
                              void* d_out, int out_size, void* d_ws, size_t ws_size,
                              hipStream_t stream) {
    const float* Pu = (const float*)d_in[0];
    const float* Po = (const float*)d_in[1];
    float* coef = (float*)d_ws;
    float* out = (float*)d_out;

    bounds_kernel<<<1, 768, 0, stream>>>(Pu, Po, coef);

    unsigned int blocks_x = (NOUT + 255u) / 256u;
    dim3 grid(blocks_x, 2, 1);
    expand_kernel<<<grid, 256, 0, stream>>>(Pu, Po, coef, out);
}

// Round 4
// 268.938 us; speedup vs baseline: 1.5925x; 1.5925x over previous
//
#include <hip/hip_runtime.h>

#define T_TERMS 768
#define NV 6
#define D1 5
#define D2 9
#define T2 (T_TERMS * T_TERMS)                 // 589824
#define PTOT (T2 + T_TERMS + 1)                // 590593
#define NROWS ((unsigned int)PTOT * NV)        // 3,543,558 rows per tensor
#define NOUT (NROWS * (unsigned int)D2)        // 31,892,022 f32 per tensor

typedef float f4 __attribute__((ext_vector_type(4)));

// Kernel 1: interval bounds l (under) and u (over) + relu relaxation coeffs.
// One block, 768 threads (one per term).
__global__ void bounds_kernel(const float* __restrict__ Pu,
                              const float* __restrict__ Po,
                              float* __restrict__ coef) {
    int t = threadIdx.x;
    float tlo = 0.f, thi = 0.f;
    if (t < T_TERMS) {
        float clo_u = 1.f, chi_u = 1.f;
        float clo_o = 1.f, chi_o = 1.f;
        const float* pu = Pu + t * NV * D1;
        const float* po = Po + t * NV * D1;
        #pragma unroll
        for (int v = 0; v < NV; ++v) {
            float lo = pu[v * 5 + 0], hi = lo;
            #pragma unroll
            for (int i = 1; i < 5; ++i) {
                float x = pu[v * 5 + i];
                lo = fminf(lo, x); hi = fmaxf(hi, x);
            }
            float a = clo_u * lo, b = clo_u * hi, c = chi_u * lo, d = chi_u * hi;
            clo_u = fminf(fminf(a, b), fminf(c, d));
            chi_u = fmaxf(fmaxf(a, b), fmaxf(c, d));
            lo = po[v * 5 + 0]; hi = lo;
            #pragma unroll
            for (int i = 1; i < 5; ++i) {
                float x = po[v * 5 + i];
                lo = fminf(lo, x); hi = fmaxf(hi, x);
            }
            a = clo_o * lo; b = clo_o * hi; c = chi_o * lo; d = chi_o * hi;
            clo_o = fminf(fminf(a, b), fminf(c, d));
            chi_o = fmaxf(fmaxf(a, b), fmaxf(c, d));
        }
        tlo = clo_u;
        thi = chi_o;
    }
    __shared__ float slo[12], shi[12];
    for (int off = 32; off; off >>= 1) {
        tlo += __shfl_down(tlo, off);
        thi += __shfl_down(thi, off);
    }
    int wave = threadIdx.x >> 6;
    if ((threadIdx.x & 63) == 0) { slo[wave] = tlo; shi[wave] = thi; }
    __syncthreads();
    if (threadIdx.x == 0) {
        float l = 0.f, u = 0.f;
        #pragma unroll
        for (int w = 0; w < 12; ++w) { l += slo[w]; u += shi[w]; }
        float den = (u - l > 0.f) ? (u - l) : 1.f;
        float au, bu, cu, ao, bo, co;
        if (l >= 0.f) {
            au = 0.f; bu = 1.f; cu = 0.f;
            ao = 0.f; bo = 1.f; co = 0.f;
        } else if (u <= 0.f) {
            au = bu = cu = 0.f;
            ao = bo = co = 0.f;
        } else {
            au = 1.f / den; bu = -l / den; cu = 0.f;
            float d2 = den * den;
            ao = u / d2; bo = -2.f * u * l / d2; co = u * l * l / d2;
        }
        coef[0] = au; coef[1] = bu; coef[2] = cu;
        coef[3] = ao; coef[4] = bo; coef[5] = co;
    }
}

// Kernel 2: one thread per output ROW (9 coeffs). Unified path:
//   sq rows:   A = P[t,v], B = P[s,v]
//   lin rows:  A = P[t,v], B = ones  (degree elevation == product with ones-poly)
//   const row: A = ones,   B = ones  (elevation of ones == ones exactly)
// scale (a/b/c on v==0) folded into A. Output staged in LDS, written as
// coalesced non-temporal dwordx4.
__global__ __launch_bounds__(256) void expand_kernel(
        const float* __restrict__ Pu,
        const float* __restrict__ Po,
        const float* __restrict__ coef,
        float* __restrict__ out) {
    __shared__ float lds[256 * D2];   // 9216 B
    static constexpr float Wt[5][5] = {
        {1.0f,        4.0f/8.0f,   6.0f/28.0f,  4.0f/56.0f,  1.0f/70.0f},
        {4.0f/8.0f,   16.0f/28.0f, 24.0f/56.0f, 16.0f/70.0f, 4.0f/56.0f},
        {6.0f/28.0f,  24.0f/56.0f, 36.0f/70.0f, 24.0f/56.0f, 6.0f/28.0f},
        {4.0f/56.0f,  16.0f/70.0f, 24.0f/56.0f, 16.0f/28.0f, 4.0f/8.0f},
        {1.0f/70.0f,  4.0f/56.0f,  6.0f/28.0f,  4.0f/8.0f,   1.0f}
    };

    const unsigned tid = threadIdx.x;
    const unsigned bid = blockIdx.x;
    const unsigned ten = blockIdx.y;          // 0 = under, 1 = over
    const float* __restrict__ P = ten ? Po : Pu;
    const float* __restrict__ c3 = coef + ten * 3;

    const unsigned rr = bid * 256u + tid;
    const unsigned nvalid = min(256u, NROWS - bid * 256u);

    float c[9] = {0.f,0.f,0.f,0.f,0.f,0.f,0.f,0.f,0.f};
    if (rr < NROWS) {
        unsigned p = rr / 6u;
        unsigned v = rr - p * 6u;
        float a[5], b[5];
        float scale = 1.f;
        if (p < (unsigned)T2) {
            unsigned t = p / (unsigned)T_TERMS;
            unsigned s = p - t * (unsigned)T_TERMS;
            const float* A = P + (t * NV + v) * D1;
            const float* B = P + (s * NV + v) * D1;
            #pragma unroll
            for (int i = 0; i < 5; ++i) { a[i] = A[i]; b[i] = B[i]; }
            if (v == 0u) scale = c3[0];
        } else if (p < (unsigned)(T2 + T_TERMS)) {
            unsigned t = p - (unsigned)T2;
            const float* A = P + (t * NV + v) * D1;
            #pragma unroll
            for (int i = 0; i < 5; ++i) { a[i] = A[i]; b[i] = 1.f; }
            if (v == 0u) scale = c3[1];
        } else {
            #pragma unroll
            for (int i = 0; i < 5; ++i) { a[i] = 1.f; b[i] = 1.f; }
            if (v == 0u) scale = c3[2];
        }
        #pragma unroll
        for (int i = 0; i < 5; ++i) a[i] *= scale;
        #pragma unroll
        for (int i = 0; i < 5; ++i)
            #pragma unroll
            for (int j = 0; j < 5; ++j)
                c[i + j] = fmaf(Wt[i][j] * a[i], b[j], c[i + j]);
    }
    #pragma unroll
    for (int k = 0; k < 9; ++k) lds[tid * 9u + k] = c[k];   // stride 9: conflict-free
    __syncthreads();

    float* __restrict__ o = out + (size_t)ten * NOUT + (size_t)bid * (256u * D2);
    const unsigned nd = nvalid * 9u;                         // dwords this block
    if (nvalid == 256u) {
        const f4* l4 = (const f4*)lds;
        f4* o4 = (f4*)o;
        __builtin_nontemporal_store(l4[tid], o4 + tid);
        __builtin_nontemporal_store(l4[tid + 256u], o4 + tid + 256u);
        if (tid < 64u)
            __builtin_nontemporal_store(l4[tid + 512u], o4 + tid + 512u);
    } else {
        for (unsigned x = tid; x < nd; x += 256u)
            __builtin_nontemporal_store(lds[x], o + x);
    }
}

extern "C" void kernel_launch(void* const* d_in, const int* in_sizes, int n_in,
                              void* d_out, int out_size, void* d_ws, size_t ws_size,
                              hipStream_t stream) {
    const float* Pu = (const float*)d_in[0];
    const float* Po = (const float*)d_in[1];
    float* coef = (float*)d_ws;
    float* out = (float*)d_out;

    bounds_kernel<<<1, 768, 0, stream>>>(Pu, Po, coef);

    unsigned int blocks_x = (NROWS + 255u) / 256u;   // 13843
    dim3 grid(blocks_x, 2, 1);
    expand_kernel<<<grid, 256, 0, stream>>>(Pu, Po, coef, out);
}

// Round 5
// 253.257 us; speedup vs baseline: 1.6911x; 1.0619x over previous
//
#include <hip/hip_runtime.h>

#define T_TERMS 768
#define NV 6
#define D1 5
#define D2 9
#define T2 (T_TERMS * T_TERMS)                 // 589824
#define PTOT (T2 + T_TERMS + 1)                // 590593
#define NROWS ((unsigned int)PTOT * NV)        // 3,543,558 rows per tensor
#define NOUT (NROWS * (unsigned int)D2)        // 31,892,022 f32 per tensor

typedef float f4 __attribute__((ext_vector_type(4)));
typedef float f4u __attribute__((ext_vector_type(4), aligned(4)));
typedef float f2 __attribute__((ext_vector_type(2)));

// Kernel 1: per-tensor interval bound. block 0: l from under (sum of mins),
// block 1: u from over (sum of maxs). 768 threads, one per term.
// Term row = 30 floats, 120B, 8-aligned -> 15x float2 loads.
__global__ void bounds_kernel(const float* __restrict__ Pu,
                              const float* __restrict__ Po,
                              float* __restrict__ ws) {
    const float* __restrict__ P = blockIdx.x ? Po : Pu;
    int t = threadIdx.x;
    float acc = 0.f;
    if (t < T_TERMS) {
        f2 r[15];
        const f2* p2 = (const f2*)(P + t * (NV * D1));
        #pragma unroll
        for (int i = 0; i < 15; ++i) r[i] = p2[i];
        const float* rf = (const float*)r;
        float clo = 1.f, chi = 1.f;
        #pragma unroll
        for (int v = 0; v < NV; ++v) {
            float lo = rf[v * 5 + 0], hi = lo;
            #pragma unroll
            for (int i = 1; i < 5; ++i) {
                float x = rf[v * 5 + i];
                lo = fminf(lo, x); hi = fmaxf(hi, x);
            }
            float a = clo * lo, b = clo * hi, c = chi * lo, d = chi * hi;
            clo = fminf(fminf(a, b), fminf(c, d));
            chi = fmaxf(fmaxf(a, b), fmaxf(c, d));
        }
        acc = blockIdx.x ? chi : clo;   // block0 -> min sum (l), block1 -> max sum (u)
    }
    __shared__ float sred[12];
    for (int off = 32; off; off >>= 1) acc += __shfl_down(acc, off);
    int wave = threadIdx.x >> 6;
    if ((threadIdx.x & 63) == 0) sred[wave] = acc;
    __syncthreads();
    if (threadIdx.x == 0) {
        float s = 0.f;
        #pragma unroll
        for (int w = 0; w < 12; ++w) s += sred[w];
        ws[blockIdx.x] = s;   // ws[0]=l, ws[1]=u
    }
}

// Kernel 1b: relu relaxation coefficients from (l,u). coef = ws+2.
__global__ void coef_kernel(float* __restrict__ ws) {
    float l = ws[0], u = ws[1];
    float den = (u - l > 0.f) ? (u - l) : 1.f;
    float au, bu, cu, ao, bo, co;
    if (l >= 0.f) {
        au = 0.f; bu = 1.f; cu = 0.f;
        ao = 0.f; bo = 1.f; co = 0.f;
    } else if (u <= 0.f) {
        au = bu = cu = 0.f;
        ao = bo = co = 0.f;
    } else {
        au = 1.f / den; bu = -l / den; cu = 0.f;
        float d2 = den * den;
        ao = u / d2; bo = -2.f * u * l / d2; co = u * l * l / d2;
    }
    float* coef = ws + 2;
    coef[0] = au; coef[1] = bu; coef[2] = cu;
    coef[3] = ao; coef[4] = bo; coef[5] = co;
}

// Kernel 2: one thread per output ROW (9 coeffs).
//   sq rows:   A = P[t,v], B = P[s,v]
//   lin rows:  A = P[t,v], B = ones  (degree elevation == product with ones)
//   const row: A = ones,   B = ones
// scale (a/b/c on v==0) folded into A. Row loads vectorized dwordx4+dword.
// Output staged in LDS (stride 9 = 2-way bank alias, free), then coalesced
// plain dwordx4 stores (fill kernel proves plain stores reach 6.4 TB/s).
__global__ __launch_bounds__(256) void expand_kernel(
        const float* __restrict__ Pu,
        const float* __restrict__ Po,
        const float* __restrict__ coef,
        float* __restrict__ out) {
    __shared__ float lds[256 * D2];   // 9216 B
    static constexpr float Wt[5][5] = {
        {1.0f,        4.0f/8.0f,   6.0f/28.0f,  4.0f/56.0f,  1.0f/70.0f},
        {4.0f/8.0f,   16.0f/28.0f, 24.0f/56.0f, 16.0f/70.0f, 4.0f/56.0f},
        {6.0f/28.0f,  24.0f/56.0f, 36.0f/70.0f, 24.0f/56.0f, 6.0f/28.0f},
        {4.0f/56.0f,  16.0f/70.0f, 24.0f/56.0f, 16.0f/28.0f, 4.0f/8.0f},
        {1.0f/70.0f,  4.0f/56.0f,  6.0f/28.0f,  4.0f/8.0f,   1.0f}
    };

    const unsigned tid = threadIdx.x;
    const unsigned bid = blockIdx.x;
    const unsigned ten = blockIdx.y;          // 0 = under, 1 = over
    const float* __restrict__ P = ten ? Po : Pu;
    const float* __restrict__ c3 = coef + ten * 3;

    const unsigned rr = bid * 256u + tid;
    const unsigned nvalid = min(256u, NROWS - bid * 256u);

    float c[9] = {0.f,0.f,0.f,0.f,0.f,0.f,0.f,0.f,0.f};
    if (rr < NROWS) {
        unsigned p = rr / 6u;
        unsigned v = rr - p * 6u;
        f4 a4; float a1;
        f4 b4; float b1;
        float scale = 1.f;
        if (p < (unsigned)T2) {
            unsigned t = p / (unsigned)T_TERMS;
            unsigned s = p - t * (unsigned)T_TERMS;
            const float* A = P + (t * NV + v) * D1;
            const float* B = P + (s * NV + v) * D1;
            a4 = *(const f4u*)A;  a1 = A[4];
            b4 = *(const f4u*)B;  b1 = B[4];
            if (v == 0u) scale = c3[0];
        } else if (p < (unsigned)(T2 + T_TERMS)) {
            unsigned t = p - (unsigned)T2;
            const float* A = P + (t * NV + v) * D1;
            a4 = *(const f4u*)A;  a1 = A[4];
            b4 = (f4){1.f,1.f,1.f,1.f};  b1 = 1.f;
            if (v == 0u) scale = c3[1];
        } else {
            a4 = (f4){1.f,1.f,1.f,1.f};  a1 = 1.f;
            b4 = (f4){1.f,1.f,1.f,1.f};  b1 = 1.f;
            if (v == 0u) scale = c3[2];
        }
        float a[5] = {a4.x * scale, a4.y * scale, a4.z * scale, a4.w * scale, a1 * scale};
        float b[5] = {b4.x, b4.y, b4.z, b4.w, b1};
        #pragma unroll
        for (int i = 0; i < 5; ++i)
            #pragma unroll
            for (int j = 0; j < 5; ++j)
                c[i + j] = fmaf(Wt[i][j] * a[i], b[j], c[i + j]);
    }
    #pragma unroll
    for (int k = 0; k < 9; ++k) lds[tid * 9u + k] = c[k];   // stride 9: 2-way, free
    __syncthreads();

    float* __restrict__ o = out + (size_t)ten * NOUT + (size_t)bid * (256u * D2);
    if (nvalid == 256u) {
        const f4* l4 = (const f4*)lds;
        f4* o4 = (f4*)o;
        o4[tid]         = l4[tid];
        o4[tid + 256u]  = l4[tid + 256u];
        if (tid < 64u)
            o4[tid + 512u] = l4[tid + 512u];
    } else {
        const unsigned nd = nvalid * 9u;
        for (unsigned x = tid; x < nd; x += 256u)
            o[x] = lds[x];
    }
}

extern "C" void kernel_launch(void* const* d_in, const int* in_sizes, int n_in,
                              void* d_out, int out_size, void* d_ws, size_t ws_size,
                              hipStream_t stream) {
    const float* Pu = (const float*)d_in[0];
    const float* Po = (const float*)d_in[1];
    float* ws = (float*)d_ws;
    float* out = (float*)d_out;

    bounds_kernel<<<2, 768, 0, stream>>>(Pu, Po, ws);
    coef_kernel<<<1, 1, 0, stream>>>(ws);

    unsigned int blocks_x = (NROWS + 255u) / 256u;   // 13843
    dim3 grid(blocks_x, 2, 1);
    expand_kernel<<<grid, 256, 0, stream>>>(Pu, Po, ws + 2, out);
}